// Round 7
// baseline (74.864 us; speedup 1.0000x reference)
//
#include <hip/hip_runtime.h>
#include <math.h>

typedef unsigned short u16;
typedef unsigned int u32;
typedef __attribute__((ext_vector_type(8))) short bf16x8;
typedef __attribute__((ext_vector_type(4))) float f32x4;

// ---------------- bf16 helpers (manual RNE; inputs are finite) ----------------
__device__ __forceinline__ u16 f2bf(float x) {
    u32 b = __builtin_bit_cast(u32, x);
    b += 0x7FFFu + ((b >> 16) & 1u);
    return (u16)(b >> 16);
}
__device__ __forceinline__ float bf2f(u16 u) {
    u32 b = ((u32)u) << 16;
    return __builtin_bit_cast(float, b);
}

// Swizzled tiled plane address, in 16-byte units.
// Plane layout: [row/128][c/64] tiles of 1024 units;
// unit-in-tile = (row&127)*8 + (slot ^ (row&7)), slot = (c&63)>>3.
__device__ __forceinline__ size_t sw_unit(int row, int c, int CC) {
    int slot = (c & 63) >> 3;
    return ((size_t)((row >> 7) * CC + (c >> 6)) << 10)
         + (size_t)((row & 127) << 3) + (size_t)(slot ^ (row & 7));
}

// ---------------------------------------------------------------------------
// prep: convert+transpose ACTIVATIONS only into swizzled hi/lo bf16 planes.
// (Weights are k-row-major already; GEMMs convert them inline while staging.)
// ---------------------------------------------------------------------------
__device__ void prep_x(const float* __restrict__ X, int C, int HW, int bl, int PT,
                       u16* __restrict__ dh, u16* __restrict__ dl) {
    __shared__ float Xt[64][65];
    const int t = threadIdx.x;
    const int pt = bl % PT, ct = bl / PT;
    const int p0 = pt * 64, c0 = ct * 64;
    const int b = p0 / HW, hw0 = p0 % HW;
    #pragma unroll
    for (int i = 0; i < 16; i++) {
        int r = (t >> 6) + i * 4;
        Xt[r][t & 63] = X[(size_t)(b * C + c0 + r) * HW + hw0 + (t & 63)];
    }
    __syncthreads();
    const int CC = C >> 6;
    #pragma unroll
    for (int it = 0; it < 2; it++) {
        int id = t + it * 256;
        int px = id >> 3, sl = id & 7;
        bf16x8 hv, lv;
        #pragma unroll
        for (int j = 0; j < 8; j++) {
            float x = Xt[sl * 8 + j][px];
            u16 h = f2bf(x);
            hv[j] = (short)h;
            lv[j] = (short)f2bf(x - bf2f(h));
        }
        size_t unit = sw_unit(p0 + px, c0 + sl * 8, CC);
        *(bf16x8*)(dh + unit * 8) = hv;
        *(bf16x8*)(dl + unit * 8) = lv;
    }
}

__global__ __launch_bounds__(256) void prep_k(
    const float* __restrict__ query, const float* __restrict__ mem0, const float* __restrict__ mem1,
    u16* Xq_hi, u16* Xq_lo, u16* Xm0_hi, u16* Xm0_lo, u16* Xm1_hi, u16* Xm1_lo)
{
    const int bx = blockIdx.x;
    if (bx < 512)      prep_x(query, 256, 4096, bx,       128, Xq_hi, Xq_lo);
    else if (bx < 704) prep_x(mem0,  384, 1024, bx - 512,  32, Xm0_hi, Xm0_lo);
    else               prep_x(mem1,  768,  256, bx - 704,   8, Xm1_hi, Xm1_lo);
}

// ---------------------------------------------------------------------------
// proj GEMM core: 64 px x 128 out tile, 4 waves (2x2 quadrants of 32x64).
// A = activation hi/lo planes (pre-swizzled); B = weights, converted inline
// from f32 rows (W[o][c] is k-major: no transpose). 3-term split MFMA.
// LDS: Ah[4096] Al[4096] Bh[8192] Bl[8192] u16 = 48 KB.
// ---------------------------------------------------------------------------
__device__ __forceinline__ void proj_core(
    const u16* __restrict__ Ahi, const u16* __restrict__ Alo,
    const float* __restrict__ W, const float* __restrict__ bias,
    u16* __restrict__ Y, int C, int CCp, int am, int bn, u16* smem)
{
    const int t = threadIdx.x, lane = t & 63, w = t >> 6;
    const int wr = w >> 1, wc = w & 1;
    const int l15 = lane & 15, kg = lane >> 4;
    const int o0 = bn * 128, p0 = am * 64;
    const int CC = C >> 6;

    u16* sAh = smem;
    u16* sAl = smem + 4096;
    u16* sBh = smem + 8192;
    u16* sBl = smem + 16384;

    f32x4 acc[2][4];
    #pragma unroll
    for (int a = 0; a < 2; a++)
        #pragma unroll
        for (int b2 = 0; b2 < 4; b2++) acc[a][b2] = (f32x4){0.f, 0.f, 0.f, 0.f};

    for (int ck = 0; ck < CC; ck++) {
        // ---- load A-plane slab (512 units x2 planes) into regs ----
        const size_t abase = ((size_t)((am >> 1) * CCp + ck) << 10) + (size_t)(am & 1) * 512;
        bf16x8 sa[2][2];
        #pragma unroll
        for (int it = 0; it < 2; it++) {
            const size_t u = (size_t)(t + it * 256);
            sa[0][it] = *(const bf16x8*)(Ahi + (abase + u) * 8);
            sa[1][it] = *(const bf16x8*)(Alo + (abase + u) * 8);
        }
        // ---- load + convert W rows (128 out x 64 c) ----
        bf16x8 wh[4], wl[4];
        int offB[4];
        #pragma unroll
        for (int it = 0; it < 4; it++) {
            const int id = t + it * 256;
            const int o = id >> 3, sl = id & 7;
            const float* wp = W + (size_t)(o0 + o) * C + ck * 64 + sl * 8;
            float4 f0 = *(const float4*)wp;
            float4 f1 = *(const float4*)(wp + 4);
            float xs[8] = {f0.x, f0.y, f0.z, f0.w, f1.x, f1.y, f1.z, f1.w};
            #pragma unroll
            for (int j = 0; j < 8; j++) {
                u16 h = f2bf(xs[j]);
                wh[it][j] = (short)h;
                wl[it][j] = (short)f2bf(xs[j] - bf2f(h));
            }
            offB[it] = o * 64 + ((sl ^ (o & 7)) << 3);
        }
        __syncthreads();   // prior chunk's reads done
        #pragma unroll
        for (int it = 0; it < 2; it++) {
            const size_t u = (size_t)(t + it * 256);
            *(bf16x8*)(sAh + u * 8) = sa[0][it];
            *(bf16x8*)(sAl + u * 8) = sa[1][it];
        }
        #pragma unroll
        for (int it = 0; it < 4; it++) {
            *(bf16x8*)(sBh + offB[it]) = wh[it];
            *(bf16x8*)(sBl + offB[it]) = wl[it];
        }
        __syncthreads();   // chunk staged

        #pragma unroll
        for (int kk = 0; kk < 2; kk++) {
            bf16x8 ah[2], al[2], bh[4], bl[4];
            #pragma unroll
            for (int tr = 0; tr < 2; tr++) {
                const int row = wr * 32 + tr * 16 + l15;
                const int off = row * 64 + (((kk * 4 + kg) ^ (row & 7)) << 3);
                ah[tr] = *(const bf16x8*)(sAh + off);
                al[tr] = *(const bf16x8*)(sAl + off);
            }
            #pragma unroll
            for (int tc = 0; tc < 4; tc++) {
                const int row = wc * 64 + tc * 16 + l15;
                const int off = row * 64 + (((kk * 4 + kg) ^ (row & 7)) << 3);
                bh[tc] = *(const bf16x8*)(sBh + off);
                bl[tc] = *(const bf16x8*)(sBl + off);
            }
            #pragma unroll
            for (int tr = 0; tr < 2; tr++)
                #pragma unroll
                for (int tc = 0; tc < 4; tc++) {
                    acc[tr][tc] = __builtin_amdgcn_mfma_f32_16x16x32_bf16(ah[tr], bh[tc], acc[tr][tc], 0, 0, 0);
                    acc[tr][tc] = __builtin_amdgcn_mfma_f32_16x16x32_bf16(al[tr], bh[tc], acc[tr][tc], 0, 0, 0);
                    acc[tr][tc] = __builtin_amdgcn_mfma_f32_16x16x32_bf16(ah[tr], bl[tc], acc[tr][tc], 0, 0, 0);
                }
        }
    }

    // ---- epilogue: D row = pixel (kg*4+i), col = out-channel (l15) ----
    float bv[4];
    #pragma unroll
    for (int tc = 0; tc < 4; tc++) bv[tc] = bias[o0 + wc * 64 + tc * 16 + l15];
    #pragma unroll
    for (int tr = 0; tr < 2; tr++) {
        #pragma unroll
        for (int i = 0; i < 4; i++) {
            const int rp = p0 + wr * 32 + tr * 16 + kg * 4 + i;
            u16* yr = Y + (size_t)rp * 256 + o0 + wc * 64 + l15;
            #pragma unroll
            for (int tc = 0; tc < 4; tc++)
                yr[tc * 16] = f2bf(acc[tr][tc][i] + bv[tc]);
        }
    }
}

// proj: q / k0 / v0 / k1 / v1 in one 416-block dispatch
__global__ __launch_bounds__(256) void projmm_k(
    const u16* __restrict__ Xq_hi, const u16* __restrict__ Xq_lo,
    const u16* __restrict__ Xm0_hi, const u16* __restrict__ Xm0_lo,
    const u16* __restrict__ Xm1_hi, const u16* __restrict__ Xm1_lo,
    const float* __restrict__ Wq,  const float* __restrict__ bq,
    const float* __restrict__ Wk0, const float* __restrict__ bk0,
    const float* __restrict__ Wv0, const float* __restrict__ bv0,
    const float* __restrict__ Wk1, const float* __restrict__ bk1,
    const float* __restrict__ Wv1, const float* __restrict__ bv1,
    u16* qT, u16* k0T, u16* v0T, u16* k1T, u16* v1T)
{
    __shared__ u16 smem[24576];   // 48 KB
    const int bx = blockIdx.x;
    const u16 *Ah, *Al; const float *W, *bias; u16* Y;
    int C, CCp, am, bn;
    if (bx < 256) {
        am = bx >> 1; bn = bx & 1; C = 256; CCp = 4;
        Ah = Xq_hi; Al = Xq_lo; W = Wq; bias = bq; Y = qT;
    } else if (bx < 384) {
        const int r = bx - 256; am = r >> 2; const int bnn = r & 3;
        C = 384; CCp = 6; Ah = Xm0_hi; Al = Xm0_lo;
        if (bnn < 2) { W = Wk0; bias = bk0; Y = k0T; bn = bnn; }
        else         { W = Wv0; bias = bv0; Y = v0T; bn = bnn - 2; }
    } else {
        const int r = bx - 384; am = r >> 2; const int bnn = r & 3;
        C = 768; CCp = 12; Ah = Xm1_hi; Al = Xm1_lo;
        if (bnn < 2) { W = Wk1; bias = bk1; Y = k1T; bn = bnn; }
        else         { W = Wv1; bias = bv1; Y = v1T; bn = bnn - 2; }
    }
    proj_core(Ah, Al, W, bias, Y, C, CCp, am, bn, smem);
}

// ---------------------------------------------------------------------------
// fuse GEMM: out[o][p] = Wfuse[o][:512]·fused[p] + bfuse.
// A = Wfuse converted inline (hi/lo); B = fused bf16 plane (hi only).
// Tile 64 rows x 128 px, 4 waves (2x2 of 32x64). LDS 32 KB. Grid 256.
// ---------------------------------------------------------------------------
__global__ __launch_bounds__(256) void fusemm_k(
    const float* __restrict__ W, const u16* __restrict__ fhi,
    const float* __restrict__ bias, float* __restrict__ out)
{
    __shared__ u16 smem[16384];   // Ah[4096] Al[4096] Bh[8192]
    u16* sAh = smem;
    u16* sAl = smem + 4096;
    u16* sBh = smem + 8192;

    const int t = threadIdx.x, lane = t & 63, w = t >> 6;
    const int wr = w >> 1, wc = w & 1;
    const int l15 = lane & 15, kg = lane >> 4;
    const int am = blockIdx.x & 3, bn = blockIdx.x >> 2;
    const int o0 = am * 64;

    f32x4 acc[2][4];
    #pragma unroll
    for (int a = 0; a < 2; a++)
        #pragma unroll
        for (int b2 = 0; b2 < 4; b2++) acc[a][b2] = (f32x4){0.f, 0.f, 0.f, 0.f};

    for (int ck = 0; ck < 8; ck++) {
        // ---- A: convert Wfuse rows (64 out x 64 c) ----
        bf16x8 wh[2], wl[2];
        int offA[2];
        #pragma unroll
        for (int it = 0; it < 2; it++) {
            const int id = t + it * 256;
            const int o = id >> 3, sl = id & 7;
            const float* wp = W + (size_t)(o0 + o) * 512 + ck * 64 + sl * 8;
            float4 f0 = *(const float4*)wp;
            float4 f1 = *(const float4*)(wp + 4);
            float xs[8] = {f0.x, f0.y, f0.z, f0.w, f1.x, f1.y, f1.z, f1.w};
            #pragma unroll
            for (int j = 0; j < 8; j++) {
                u16 h = f2bf(xs[j]);
                wh[it][j] = (short)h;
                wl[it][j] = (short)f2bf(xs[j] - bf2f(h));
            }
            offA[it] = o * 64 + ((sl ^ (o & 7)) << 3);
        }
        // ---- B: copy fused-plane slab (1024 units) ----
        const size_t bbase = (size_t)(bn * 8 + ck) << 10;
        bf16x8 sb[4];
        #pragma unroll
        for (int it = 0; it < 4; it++)
            sb[it] = *(const bf16x8*)(fhi + (bbase + (size_t)(t + it * 256)) * 8);
        __syncthreads();
        #pragma unroll
        for (int it = 0; it < 2; it++) {
            *(bf16x8*)(sAh + offA[it]) = wh[it];
            *(bf16x8*)(sAl + offA[it]) = wl[it];
        }
        #pragma unroll
        for (int it = 0; it < 4; it++)
            *(bf16x8*)(sBh + (size_t)(t + it * 256) * 8) = sb[it];
        __syncthreads();

        #pragma unroll
        for (int kk = 0; kk < 2; kk++) {
            bf16x8 ah[2], al[2], bh[4];
            #pragma unroll
            for (int tr = 0; tr < 2; tr++) {
                const int row = wr * 32 + tr * 16 + l15;
                const int off = row * 64 + (((kk * 4 + kg) ^ (row & 7)) << 3);
                ah[tr] = *(const bf16x8*)(sAh + off);
                al[tr] = *(const bf16x8*)(sAl + off);
            }
            #pragma unroll
            for (int tc = 0; tc < 4; tc++) {
                const int row = wc * 64 + tc * 16 + l15;
                const int off = row * 64 + (((kk * 4 + kg) ^ (row & 7)) << 3);
                bh[tc] = *(const bf16x8*)(sBh + off);
            }
            #pragma unroll
            for (int tr = 0; tr < 2; tr++)
                #pragma unroll
                for (int tc = 0; tc < 4; tc++) {
                    acc[tr][tc] = __builtin_amdgcn_mfma_f32_16x16x32_bf16(ah[tr], bh[tc], acc[tr][tc], 0, 0, 0);
                    acc[tr][tc] = __builtin_amdgcn_mfma_f32_16x16x32_bf16(al[tr], bh[tc], acc[tr][tc], 0, 0, 0);
                }
        }
    }

    // ---- epilogue: D row = out-channel, col = pixel; out channel-major ----
    #pragma unroll
    for (int tr = 0; tr < 2; tr++) {
        #pragma unroll
        for (int i = 0; i < 4; i++) {
            const int o = o0 + wr * 32 + tr * 16 + kg * 4 + i;
            const float bv = bias[o];
            #pragma unroll
            for (int tc = 0; tc < 4; tc++) {
                const int pcol = bn * 128 + wc * 64 + tc * 16 + l15;
                out[(size_t)((pcol >> 12) * 256 + o) * 4096 + (pcol & 4095)] = acc[tr][tc][i] + bv;
            }
        }
    }
}

// ---------------------------------------------------------------------------
// MFMA attention (unchanged from R5, validated). One wave per (b, head, 4x4
// query tile); 8x8 candidate superset, mask to window+borders; S then P·V.
// ---------------------------------------------------------------------------
template<int SCALE>
__device__ __forceinline__ void attn_mfma(
    const u16* __restrict__ qT, const u16* __restrict__ kT,
    const u16* __restrict__ vT, u16* __restrict__ fhi,
    int b, int n, int ty, int tx, int lane, u16* s_lds)
{
    constexpr int HM = SCALE ? 16 : 32;
    const int qy0 = ty * 4, qx0 = tx * 4;
    const int ay0 = SCALE ? (qy0 >> 2) : (qy0 >> 1);
    const int ax0 = SCALE ? (qx0 >> 2) : (qx0 >> 1);
    const int l15 = lane & 15, kg = lane >> 4;

    const int pA = (b * 64 + qy0 + (l15 >> 2)) * 64 + qx0 + (l15 & 3);
    const bf16x8 qf = *(const bf16x8*)(qT + (size_t)pA * 256 + n * 32 + kg * 8);

    f32x4 s[4];
    #pragma unroll
    for (int t = 0; t < 4; t++) {
        const int cand = t * 16 + l15;
        const int wy = cand >> 3, wx = cand & 7;
        const int my = SCALE ? (ay0 + (wy - 2) * 2) : (ay0 - 3 + wy);
        const int mx = SCALE ? (ax0 + (wx - 2) * 2) : (ax0 - 3 + wx);
        const int myc = min(max(my, 0), HM - 1), mxc = min(max(mx, 0), HM - 1);
        const bf16x8 kf = *(const bf16x8*)(kT + (size_t)((b * HM + myc) * HM + mxc) * 256 + n * 32 + kg * 8);
        s[t] = __builtin_amdgcn_mfma_f32_16x16x32_bf16(qf, kf, (f32x4){0.f, 0.f, 0.f, 0.f}, 0, 0, 0);
    }

    const float scl = 0.17677669529663687f;
    float sv[4][4];
    #pragma unroll
    for (int t = 0; t < 4; t++) {
        const int cand = t * 16 + l15;
        const int wy = cand >> 3, wx = cand & 7;
        const int my = SCALE ? (ay0 + (wy - 2) * 2) : (ay0 - 3 + wy);
        const int mx = SCALE ? (ax0 + (wx - 2) * 2) : (ax0 - 3 + wx);
        const bool inb = (my >= 0) && (my < HM) && (mx >= 0) && (mx < HM);
        #pragma unroll
        for (int i = 0; i < 4; i++) {
            bool ok;
            if (SCALE) {
                ok = inb && (wy < 5) && (wx < 5);
            } else {
                const int r = kg * 4 + i;
                const int dy2 = (r >> 2) >> 1, dx2 = (r & 3) >> 1;
                ok = inb && ((u32)(wy - dy2) <= 6u) && ((u32)(wx - dx2) <= 6u);
            }
            sv[t][i] = ok ? s[t][i] * scl : -1e30f;
        }
    }

    float linv[4];
    #pragma unroll
    for (int i = 0; i < 4; i++) {
        float m = fmaxf(fmaxf(sv[0][i], sv[1][i]), fmaxf(sv[2][i], sv[3][i]));
        #pragma unroll
        for (int dd = 1; dd < 16; dd <<= 1) m = fmaxf(m, __shfl_xor(m, dd, 64));
        float l = 0.f;
        #pragma unroll
        for (int t = 0; t < 4; t++) { sv[t][i] = __expf(sv[t][i] - m); l += sv[t][i]; }
        #pragma unroll
        for (int dd = 1; dd < 16; dd <<= 1) l += __shfl_xor(l, dd, 64);
        linv[i] = 1.f / l;
    }

    #pragma unroll
    for (int t = 0; t < 4; t++)
        #pragma unroll
        for (int i = 0; i < 4; i++)
            s_lds[(kg * 4 + i) * 68 + t * 16 + l15] = f2bf(sv[t][i]);
    __syncthreads();

    f32x4 o[2] = {(f32x4){0.f,0.f,0.f,0.f}, (f32x4){0.f,0.f,0.f,0.f}};
    #pragma unroll
    for (int h = 0; h < 2; h++) {
        const bf16x8 pa = *(const bf16x8*)(s_lds + l15 * 68 + h * 32 + kg * 8);
        #pragma unroll
        for (int c = 0; c < 2; c++) {
            bf16x8 vf;
            #pragma unroll
            for (int j = 0; j < 8; j++) {
                const int cand = h * 32 + kg * 8 + j;
                const int wy = cand >> 3, wx = cand & 7;
                int my = SCALE ? (ay0 + (wy - 2) * 2) : (ay0 - 3 + wy);
                int mx = SCALE ? (ax0 + (wx - 2) * 2) : (ax0 - 3 + wx);
                my = min(max(my, 0), HM - 1); mx = min(max(mx, 0), HM - 1);
                vf[j] = (short)vT[(size_t)((b * HM + my) * HM + mx) * 256 + n * 32 + c * 16 + l15];
            }
            o[c] = __builtin_amdgcn_mfma_f32_16x16x32_bf16(pa, vf, o[c], 0, 0, 0);
        }
    }

    #pragma unroll
    for (int c = 0; c < 2; c++) {
        #pragma unroll
        for (int i = 0; i < 4; i++) {
            const int r = kg * 4 + i;
            const int p = (b * 64 + qy0 + (r >> 2)) * 64 + qx0 + (r & 3);
            const int ch = (SCALE ? 256 : 0) + n * 32 + c * 16 + l15;
            fhi[sw_unit(p, ch, 8) * 8 + (ch & 7)] = f2bf(o[c][i] * linv[i]);
        }
    }
}

__global__ __launch_bounds__(256) void attn_k(
    const u16* __restrict__ qT,
    const u16* __restrict__ k0T, const u16* __restrict__ v0T,
    const u16* __restrict__ k1T, const u16* __restrict__ v1T,
    u16* __restrict__ fhi)
{
    __shared__ u16 s_lds[4][16 * 68];
    const int t = threadIdx.x, w = t >> 6, lane = t & 63;
    const int bx = blockIdx.x;
    const int sc = bx >> 10;
    const int tile = (bx & 1023) * 4 + w;
    const int b = tile >> 11, n = (tile >> 8) & 7;
    const int ty = (tile >> 4) & 15, tx = tile & 15;
    if (sc == 0) attn_mfma<0>(qT, k0T, v0T, fhi, b, n, ty, tx, lane, s_lds[w]);
    else         attn_mfma<1>(qT, k1T, v1T, fhi, b, n, ty, tx, lane, s_lds[w]);
}

// ---------------------------------------------------------------------------
extern "C" void kernel_launch(void* const* d_in, const int* in_sizes, int n_in,
                              void* d_out, int out_size, void* d_ws, size_t ws_size,
                              hipStream_t stream)
{
    const float* query = (const float*)d_in[0];
    const float* mem0  = (const float*)d_in[1];
    const float* mem1  = (const float*)d_in[2];
    const float* Wq    = (const float*)d_in[3];  const float* bq    = (const float*)d_in[4];
    const float* Wk0   = (const float*)d_in[5];  const float* bk0   = (const float*)d_in[6];
    const float* Wv0   = (const float*)d_in[7];  const float* bv0   = (const float*)d_in[8];
    const float* Wk1   = (const float*)d_in[9];  const float* bk1   = (const float*)d_in[10];
    const float* Wv1   = (const float*)d_in[11]; const float* bv1   = (const float*)d_in[12];
    const float* Wfuse = (const float*)d_in[13]; const float* bfuse = (const float*)d_in[14];
    float* out = (float*)d_out;

    char* ws = (char*)d_ws;
    u16* qT       = (u16*)(ws + 0);            // 4 MB (bf16 pixel-major)
    u16* k0T      = (u16*)(ws + 8388608);      // 1 MB
    u16* v0T      = (u16*)(ws + 10485760);     // 1 MB
    u16* k1T      = (u16*)(ws + 12582912);     // 256 KB
    u16* v1T      = (u16*)(ws + 13107200);     // 256 KB
    u16* Xm0_hi   = (u16*)(ws + 16777216);
    u16* Xm0_lo   = (u16*)(ws + 18350080);
    u16* Xm1_hi   = (u16*)(ws + 19922944);
    u16* Xm1_lo   = (u16*)(ws + 20709376);
    u16* Xq_hi    = (u16*)(ws + 21495808);     // 4 MB
    u16* Xq_lo    = (u16*)(ws + 25690112);     // 4 MB
    u16* fhi      = Xq_hi;                     // fused plane (8 MB) aliases Xq planes

    prep_k<<<dim3(800), 256, 0, stream>>>(
        query, mem0, mem1, Xq_hi, Xq_lo, Xm0_hi, Xm0_lo, Xm1_hi, Xm1_lo);

    projmm_k<<<dim3(416), 256, 0, stream>>>(
        Xq_hi, Xq_lo, Xm0_hi, Xm0_lo, Xm1_hi, Xm1_lo,
        Wq, bq, Wk0, bk0, Wv0, bv0, Wk1, bk1, Wv1, bv1,
        qT, k0T, v0T, k1T, v1T);

    attn_k<<<dim3(2048), 256, 0, stream>>>(qT, k0T, v0T, k1T, v1T, fhi);

    fusemm_k<<<dim3(256), 256, 0, stream>>>(Wfuse, fhi, bfuse, out);
}

// Round 9
// 68.968 us; speedup vs baseline: 1.0855x; 1.0855x over previous
//
#include <hip/hip_runtime.h>
#include <math.h>

typedef unsigned short u16;
typedef unsigned int u32;
typedef __attribute__((ext_vector_type(8))) short bf16x8;
typedef __attribute__((ext_vector_type(4))) float f32x4;

// ---------------- bf16 helpers (manual RNE; inputs are finite) ----------------
__device__ __forceinline__ u16 f2bf(float x) {
    u32 b = __builtin_bit_cast(u32, x);
    b += 0x7FFFu + ((b >> 16) & 1u);
    return (u16)(b >> 16);
}
__device__ __forceinline__ float bf2f(u16 u) {
    u32 b = ((u32)u) << 16;
    return __builtin_bit_cast(float, b);
}

// Swizzled tiled plane address, in 16-byte units.
// Plane layout: [row/128][c/64] tiles of 1024 units;
// unit-in-tile = (row&127)*8 + (slot ^ (row&7)), slot = (c&63)>>3.
__device__ __forceinline__ size_t sw_unit(int row, int c, int CC) {
    int slot = (c & 63) >> 3;
    return ((size_t)((row >> 7) * CC + (c >> 6)) << 10)
         + (size_t)((row & 127) << 3) + (size_t)(slot ^ (row & 7));
}

// ---------------------------------------------------------------------------
// prep: convert+transpose activations / convert weights into swizzled hi/lo
// bf16 planes. (R5-proven.)
// ---------------------------------------------------------------------------
__device__ void prep_x(const float* __restrict__ X, int C, int HW, int bl, int PT,
                       u16* __restrict__ dh, u16* __restrict__ dl) {
    __shared__ float Xt[64][65];
    const int t = threadIdx.x;
    const int pt = bl % PT, ct = bl / PT;
    const int p0 = pt * 64, c0 = ct * 64;
    const int b = p0 / HW, hw0 = p0 % HW;
    #pragma unroll
    for (int i = 0; i < 16; i++) {
        int r = (t >> 6) + i * 4;
        Xt[r][t & 63] = X[(size_t)(b * C + c0 + r) * HW + hw0 + (t & 63)];
    }
    __syncthreads();
    const int CC = C >> 6;
    #pragma unroll
    for (int it = 0; it < 2; it++) {
        int id = t + it * 256;
        int px = id >> 3, sl = id & 7;
        bf16x8 hv, lv;
        #pragma unroll
        for (int j = 0; j < 8; j++) {
            float x = Xt[sl * 8 + j][px];
            u16 h = f2bf(x);
            hv[j] = (short)h;
            lv[j] = (short)f2bf(x - bf2f(h));
        }
        size_t unit = sw_unit(p0 + px, c0 + sl * 8, CC);
        *(bf16x8*)(dh + unit * 8) = hv;
        *(bf16x8*)(dl + unit * 8) = lv;
    }
}

__device__ void prep_w(const float* __restrict__ W, int C, int bl,
                       u16* __restrict__ dh, u16* __restrict__ dl) {
    const int t = threadIdx.x;
    const int ot = bl & 3, cc = bl >> 2;
    const int o0 = ot * 64, c0 = cc * 64;
    const int CC = C >> 6;
    #pragma unroll
    for (int it = 0; it < 2; it++) {
        int id = t + it * 256;
        int ol = id >> 3, sl = id & 7;
        int o = o0 + ol, c = c0 + sl * 8;
        const float* wp = W + (size_t)o * C + c;
        float4 a = *(const float4*)wp;
        float4 b2 = *(const float4*)(wp + 4);
        float xs[8] = {a.x, a.y, a.z, a.w, b2.x, b2.y, b2.z, b2.w};
        bf16x8 hv, lv;
        #pragma unroll
        for (int j = 0; j < 8; j++) {
            u16 h = f2bf(xs[j]);
            hv[j] = (short)h;
            lv[j] = (short)f2bf(xs[j] - bf2f(h));
        }
        size_t unit = sw_unit(o, c, CC);
        *(bf16x8*)(dh + unit * 8) = hv;
        *(bf16x8*)(dl + unit * 8) = lv;
    }
}

// W plane offsets in u16 units inside the combined Whi/Wlo buffers
#define OFF_WQ 0
#define OFF_WK0 65536
#define OFF_WV0 163840
#define OFF_WK1 262144
#define OFF_WV1 458752
#define OFF_WFUSE 655360

__global__ __launch_bounds__(256) void prep_k(
    const float* __restrict__ query, const float* __restrict__ mem0, const float* __restrict__ mem1,
    const float* __restrict__ Wq, const float* __restrict__ Wk0, const float* __restrict__ Wv0,
    const float* __restrict__ Wk1, const float* __restrict__ Wv1, const float* __restrict__ Wfuse,
    u16* Xq_hi, u16* Xq_lo, u16* Xm0_hi, u16* Xm0_lo, u16* Xm1_hi, u16* Xm1_lo,
    u16* Whi, u16* Wlo)
{
    const int bx = blockIdx.x;
    if (bx < 512)      prep_x(query, 256, 4096, bx,       128, Xq_hi, Xq_lo);
    else if (bx < 704) prep_x(mem0,  384, 1024, bx - 512,  32, Xm0_hi, Xm0_lo);
    else if (bx < 800) prep_x(mem1,  768,  256, bx - 704,   8, Xm1_hi, Xm1_lo);
    else {
        int r = bx - 800;
        if (r < 16)       prep_w(Wq,    256, r,       Whi + OFF_WQ,    Wlo + OFF_WQ);
        else if (r < 40)  prep_w(Wk0,   384, r - 16,  Whi + OFF_WK0,   Wlo + OFF_WK0);
        else if (r < 64)  prep_w(Wv0,   384, r - 40,  Whi + OFF_WV0,   Wlo + OFF_WV0);
        else if (r < 112) prep_w(Wk1,   768, r - 64,  Whi + OFF_WK1,   Wlo + OFF_WK1);
        else if (r < 160) prep_w(Wv1,   768, r - 112, Whi + OFF_WV1,   Wlo + OFF_WV1);
        else              prep_w(Wfuse, 512, r - 160, Whi + OFF_WFUSE, Wlo + OFF_WFUSE);
    }
}

// ---------------------------------------------------------------------------
// Split-bf16 MFMA GEMM core, SOFTWARE-PIPELINED (2-phase): prologue-load
// chunk0 to regs; per iteration {write LDS, barrier, ISSUE next-chunk loads,
// MFMA on current}. Chunk-load latency hides under the MFMA phase.
// Block = 128x128, 4 waves of 64x64 (4x4 16x16 D-tiles), KC=64.
// BPL=2: 3-term split. BPL=1: B hi-only.
// ---------------------------------------------------------------------------
template<int BPL, bool OUT16>
__device__ __forceinline__ void gemm_core(
    const u16* __restrict__ Ahi, const u16* __restrict__ Alo,
    const u16* __restrict__ Bhi, const u16* __restrict__ Blo,
    const float* __restrict__ bias, void* __restrict__ Y,
    int CC, int am, int bn, u16* smem)
{
    constexpr int PL = 2 + BPL;
    const int t = threadIdx.x, lane = t & 63, w = t >> 6;
    const int wr = w >> 1, wc = w & 1;

    f32x4 acc[4][4];
    #pragma unroll
    for (int a = 0; a < 4; a++)
        #pragma unroll
        for (int b = 0; b < 4; b++)
            acc[a][b] = (f32x4){0.f, 0.f, 0.f, 0.f};

    bf16x8 stg[PL][4];
    // ---- prologue: load chunk 0 ----
    {
        const size_t aoff = ((size_t)(am * CC)) << 13;
        const size_t boff = ((size_t)(bn * CC)) << 13;
        #pragma unroll
        for (int it = 0; it < 4; it++) {
            const size_t o = (size_t)(t + it * 256) * 8;
            stg[0][it] = *(const bf16x8*)(Ahi + aoff + o);
            stg[1][it] = *(const bf16x8*)(Alo + aoff + o);
            stg[2][it] = *(const bf16x8*)(Bhi + boff + o);
            if (BPL == 2) stg[3][it] = *(const bf16x8*)(Blo + boff + o);
        }
    }

    for (int ck = 0; ck < CC; ck++) {
        __syncthreads();   // prior chunk's LDS reads done
        #pragma unroll
        for (int p = 0; p < PL; p++)
            #pragma unroll
            for (int it = 0; it < 4; it++)
                *(bf16x8*)(smem + p * 8192 + (size_t)(t + it * 256) * 8) = stg[p][it];
        __syncthreads();   // chunk staged

        // ---- prefetch next chunk (clamped; last-iter re-read is harmless) ----
        {
            const int cn = (ck + 1 < CC) ? ck + 1 : ck;
            const size_t aoff = ((size_t)(am * CC + cn)) << 13;
            const size_t boff = ((size_t)(bn * CC + cn)) << 13;
            #pragma unroll
            for (int it = 0; it < 4; it++) {
                const size_t o = (size_t)(t + it * 256) * 8;
                stg[0][it] = *(const bf16x8*)(Ahi + aoff + o);
                stg[1][it] = *(const bf16x8*)(Alo + aoff + o);
                stg[2][it] = *(const bf16x8*)(Bhi + boff + o);
                if (BPL == 2) stg[3][it] = *(const bf16x8*)(Blo + boff + o);
            }
        }

        // ---- compute: 2 k-steps of 32 ----
        #pragma unroll
        for (int kk = 0; kk < 2; kk++) {
            bf16x8 ah[4], al[4], bh[4], bl[4];
            #pragma unroll
            for (int tr = 0; tr < 4; tr++) {
                int row = wr * 64 + tr * 16 + (lane & 15);
                int off = row * 64 + (((kk * 4 + (lane >> 4)) ^ (row & 7)) << 3);
                ah[tr] = *(const bf16x8*)(smem + off);
                al[tr] = *(const bf16x8*)(smem + 8192 + off);
            }
            #pragma unroll
            for (int tc = 0; tc < 4; tc++) {
                int row = wc * 64 + tc * 16 + (lane & 15);
                int off = row * 64 + (((kk * 4 + (lane >> 4)) ^ (row & 7)) << 3);
                bh[tc] = *(const bf16x8*)(smem + 16384 + off);
                if (BPL == 2) bl[tc] = *(const bf16x8*)(smem + 24576 + off);
            }
            #pragma unroll
            for (int tr = 0; tr < 4; tr++)
                #pragma unroll
                for (int tc = 0; tc < 4; tc++) {
                    acc[tr][tc] = __builtin_amdgcn_mfma_f32_16x16x32_bf16(ah[tr], bh[tc], acc[tr][tc], 0, 0, 0);
                    acc[tr][tc] = __builtin_amdgcn_mfma_f32_16x16x32_bf16(al[tr], bh[tc], acc[tr][tc], 0, 0, 0);
                    if (BPL == 2)
                        acc[tr][tc] = __builtin_amdgcn_mfma_f32_16x16x32_bf16(ah[tr], bl[tc], acc[tr][tc], 0, 0, 0);
                }
        }
    }

    // ---- epilogue: D row = (lane>>4)*4+i, col = lane&15 (m89-verified) ----
    if (OUT16) {
        u16* Y16 = (u16*)Y;
        float bv[4];
        #pragma unroll
        for (int tc = 0; tc < 4; tc++)
            bv[tc] = bias[bn * 128 + wc * 64 + tc * 16 + (lane & 15)];
        #pragma unroll
        for (int tr = 0; tr < 4; tr++) {
            #pragma unroll
            for (int i = 0; i < 4; i++) {
                int rp = am * 128 + wr * 64 + tr * 16 + ((lane >> 4) << 2) + i;
                u16* yr = Y16 + (size_t)rp * 256 + bn * 128 + wc * 64 + (lane & 15);
                #pragma unroll
                for (int tc = 0; tc < 4; tc++)
                    yr[tc * 16] = f2bf(acc[tr][tc][i] + bv[tc]);
            }
        }
    } else {
        float* Yf = (float*)Y;
        #pragma unroll
        for (int tr = 0; tr < 4; tr++) {
            #pragma unroll
            for (int i = 0; i < 4; i++) {
                int o = am * 128 + wr * 64 + tr * 16 + ((lane >> 4) << 2) + i;
                float bv = bias[o];
                #pragma unroll
                for (int tc = 0; tc < 4; tc++) {
                    int pcol = bn * 128 + wc * 64 + tc * 16 + (lane & 15);
                    Yf[(size_t)((pcol >> 12) * 256 + o) * 4096 + (pcol & 4095)] = acc[tr][tc][i] + bv;
                }
            }
        }
    }
}

__global__ __launch_bounds__(256) void projmm_k(
    const u16* __restrict__ Xq_hi, const u16* __restrict__ Xq_lo,
    const u16* __restrict__ Xm0_hi, const u16* __restrict__ Xm0_lo,
    const u16* __restrict__ Xm1_hi, const u16* __restrict__ Xm1_lo,
    const u16* __restrict__ Whi, const u16* __restrict__ Wlo,
    const float* __restrict__ bq, const float* __restrict__ bk0, const float* __restrict__ bv0,
    const float* __restrict__ bk1, const float* __restrict__ bv1,
    u16* qT, u16* k0T, u16* v0T, u16* k1T, u16* v1T)
{
    __shared__ u16 smem[32768];
    const int bx = blockIdx.x;
    const u16 *Ah, *Al, *Bh, *Bl; const float* bias; u16* Y;
    int CC, am, bn;
    if (bx < 128) {
        am = bx >> 1; bn = bx & 1; CC = 4;
        Ah = Xq_hi; Al = Xq_lo; Bh = Whi + OFF_WQ; Bl = Wlo + OFF_WQ; bias = bq; Y = qT;
    } else if (bx < 192) {
        int r = bx - 128; am = r >> 2; int bnn = r & 3; CC = 6;
        Ah = Xm0_hi; Al = Xm0_lo;
        if (bnn < 2) { Bh = Whi + OFF_WK0; Bl = Wlo + OFF_WK0; bias = bk0; Y = k0T; bn = bnn; }
        else         { Bh = Whi + OFF_WV0; Bl = Wlo + OFF_WV0; bias = bv0; Y = v0T; bn = bnn - 2; }
    } else {
        int r = bx - 192; am = r >> 2; int bnn = r & 3; CC = 12;
        Ah = Xm1_hi; Al = Xm1_lo;
        if (bnn < 2) { Bh = Whi + OFF_WK1; Bl = Wlo + OFF_WK1; bias = bk1; Y = k1T; bn = bnn; }
        else         { Bh = Whi + OFF_WV1; Bl = Wlo + OFF_WV1; bias = bv1; Y = v1T; bn = bnn - 2; }
    }
    gemm_core<2, true>(Ah, Al, Bh, Bl, bias, (void*)Y, CC, am, bn, smem);
}

__global__ __launch_bounds__(256) void fusemm_k(
    const u16* __restrict__ Whi, const u16* __restrict__ Wlo,
    const u16* __restrict__ fhi, const float* __restrict__ bfuse, float* out)
{
    __shared__ u16 smem[24576];
    const int bx = blockIdx.x;
    gemm_core<1, false>(Whi + OFF_WFUSE, Wlo + OFF_WFUSE, fhi, (const u16*)nullptr,
                        bfuse, (void*)out, 8, bx & 1, bx >> 1, smem);
}

// ---------------------------------------------------------------------------
// MFMA attention (R5-proven, unchanged). One wave per (b, head, 4x4 q-tile);
// 8x8 candidate superset, mask to window+borders; S = Q·K^T then O = P·V.
// ---------------------------------------------------------------------------
template<int SCALE>
__device__ __forceinline__ void attn_mfma(
    const u16* __restrict__ qT, const u16* __restrict__ kT,
    const u16* __restrict__ vT, u16* __restrict__ fhi,
    int b, int n, int ty, int tx, int lane, u16* s_lds)
{
    constexpr int HM = SCALE ? 16 : 32;
    const int qy0 = ty * 4, qx0 = tx * 4;
    const int ay0 = SCALE ? (qy0 >> 2) : (qy0 >> 1);
    const int ax0 = SCALE ? (qx0 >> 2) : (qx0 >> 1);
    const int l15 = lane & 15, kg = lane >> 4;

    const int pA = (b * 64 + qy0 + (l15 >> 2)) * 64 + qx0 + (l15 & 3);
    const bf16x8 qf = *(const bf16x8*)(qT + (size_t)pA * 256 + n * 32 + kg * 8);

    f32x4 s[4];
    #pragma unroll
    for (int t = 0; t < 4; t++) {
        const int cand = t * 16 + l15;
        const int wy = cand >> 3, wx = cand & 7;
        const int my = SCALE ? (ay0 + (wy - 2) * 2) : (ay0 - 3 + wy);
        const int mx = SCALE ? (ax0 + (wx - 2) * 2) : (ax0 - 3 + wx);
        const int myc = min(max(my, 0), HM - 1), mxc = min(max(mx, 0), HM - 1);
        const bf16x8 kf = *(const bf16x8*)(kT + (size_t)((b * HM + myc) * HM + mxc) * 256 + n * 32 + kg * 8);
        s[t] = __builtin_amdgcn_mfma_f32_16x16x32_bf16(qf, kf, (f32x4){0.f, 0.f, 0.f, 0.f}, 0, 0, 0);
    }

    const float scl = 0.17677669529663687f;
    float sv[4][4];
    #pragma unroll
    for (int t = 0; t < 4; t++) {
        const int cand = t * 16 + l15;
        const int wy = cand >> 3, wx = cand & 7;
        const int my = SCALE ? (ay0 + (wy - 2) * 2) : (ay0 - 3 + wy);
        const int mx = SCALE ? (ax0 + (wx - 2) * 2) : (ax0 - 3 + wx);
        const bool inb = (my >= 0) && (my < HM) && (mx >= 0) && (mx < HM);
        #pragma unroll
        for (int i = 0; i < 4; i++) {
            bool ok;
            if (SCALE) {
                ok = inb && (wy < 5) && (wx < 5);
            } else {
                const int r = kg * 4 + i;
                const int dy2 = (r >> 2) >> 1, dx2 = (r & 3) >> 1;
                ok = inb && ((u32)(wy - dy2) <= 6u) && ((u32)(wx - dx2) <= 6u);
            }
            sv[t][i] = ok ? s[t][i] * scl : -1e30f;
        }
    }

    float linv[4];
    #pragma unroll
    for (int i = 0; i < 4; i++) {
        float m = fmaxf(fmaxf(sv[0][i], sv[1][i]), fmaxf(sv[2][i], sv[3][i]));
        #pragma unroll
        for (int dd = 1; dd < 16; dd <<= 1) m = fmaxf(m, __shfl_xor(m, dd, 64));
        float l = 0.f;
        #pragma unroll
        for (int t = 0; t < 4; t++) { sv[t][i] = __expf(sv[t][i] - m); l += sv[t][i]; }
        #pragma unroll
        for (int dd = 1; dd < 16; dd <<= 1) l += __shfl_xor(l, dd, 64);
        linv[i] = 1.f / l;
    }

    #pragma unroll
    for (int t = 0; t < 4; t++)
        #pragma unroll
        for (int i = 0; i < 4; i++)
            s_lds[(kg * 4 + i) * 68 + t * 16 + l15] = f2bf(sv[t][i]);
    __syncthreads();

    f32x4 o[2] = {(f32x4){0.f,0.f,0.f,0.f}, (f32x4){0.f,0.f,0.f,0.f}};
    #pragma unroll
    for (int h = 0; h < 2; h++) {
        const bf16x8 pa = *(const bf16x8*)(s_lds + l15 * 68 + h * 32 + kg * 8);
        #pragma unroll
        for (int c = 0; c < 2; c++) {
            bf16x8 vf;
            #pragma unroll
            for (int j = 0; j < 8; j++) {
                const int cand = h * 32 + kg * 8 + j;
                const int wy = cand >> 3, wx = cand & 7;
                int my = SCALE ? (ay0 + (wy - 2) * 2) : (ay0 - 3 + wy);
                int mx = SCALE ? (ax0 + (wx - 2) * 2) : (ax0 - 3 + wx);
                my = min(max(my, 0), HM - 1); mx = min(max(mx, 0), HM - 1);
                vf[j] = (short)vT[(size_t)((b * HM + my) * HM + mx) * 256 + n * 32 + c * 16 + l15];
            }
            o[c] = __builtin_amdgcn_mfma_f32_16x16x32_bf16(pa, vf, o[c], 0, 0, 0);
        }
    }

    #pragma unroll
    for (int c = 0; c < 2; c++) {
        #pragma unroll
        for (int i = 0; i < 4; i++) {
            const int r = kg * 4 + i;
            const int p = (b * 64 + qy0 + (r >> 2)) * 64 + qx0 + (r & 3);
            const int ch = (SCALE ? 256 : 0) + n * 32 + c * 16 + l15;
            fhi[sw_unit(p, ch, 8) * 8 + (ch & 7)] = f2bf(o[c][i] * linv[i]);
        }
    }
}

__global__ __launch_bounds__(256) void attn_k(
    const u16* __restrict__ qT,
    const u16* __restrict__ k0T, const u16* __restrict__ v0T,
    const u16* __restrict__ k1T, const u16* __restrict__ v1T,
    u16* __restrict__ fhi)
{
    __shared__ u16 s_lds[4][16 * 68];
    const int t = threadIdx.x, w = t >> 6, lane = t & 63;
    const int bx = blockIdx.x;
    const int sc = bx >> 10;
    const int tile = (bx & 1023) * 4 + w;
    const int b = tile >> 11, n = (tile >> 8) & 7;
    const int ty = (tile >> 4) & 15, tx = tile & 15;
    if (sc == 0) attn_mfma<0>(qT, k0T, v0T, fhi, b, n, ty, tx, lane, s_lds[w]);
    else         attn_mfma<1>(qT, k1T, v1T, fhi, b, n, ty, tx, lane, s_lds[w]);
}

// ---------------------------------------------------------------------------
extern "C" void kernel_launch(void* const* d_in, const int* in_sizes, int n_in,
                              void* d_out, int out_size, void* d_ws, size_t ws_size,
                              hipStream_t stream)
{
    const float* query = (const float*)d_in[0];
    const float* mem0  = (const float*)d_in[1];
    const float* mem1  = (const float*)d_in[2];
    const float* Wq    = (const float*)d_in[3];  const float* bq    = (const float*)d_in[4];
    const float* Wk0   = (const float*)d_in[5];  const float* bk0   = (const float*)d_in[6];
    const float* Wv0   = (const float*)d_in[7];  const float* bv0   = (const float*)d_in[8];
    const float* Wk1   = (const float*)d_in[9];  const float* bk1   = (const float*)d_in[10];
    const float* Wv1   = (const float*)d_in[11]; const float* bv1   = (const float*)d_in[12];
    const float* Wfuse = (const float*)d_in[13]; const float* bfuse = (const float*)d_in[14];
    float* out = (float*)d_out;

    char* ws = (char*)d_ws;
    u16* qT       = (u16*)(ws + 0);            // 4 MB (bf16 pixel-major)
    u16* k0T      = (u16*)(ws + 8388608);      // 1 MB
    u16* v0T      = (u16*)(ws + 10485760);     // 1 MB
    u16* k1T      = (u16*)(ws + 12582912);     // 256 KB
    u16* v1T      = (u16*)(ws + 13107200);     // 256 KB
    u16* Whi      = (u16*)(ws + 13631488);
    u16* Wlo      = (u16*)(ws + 15204352);
    u16* Xm0_hi   = (u16*)(ws + 16777216);
    u16* Xm0_lo   = (u16*)(ws + 18350080);
    u16* Xm1_hi   = (u16*)(ws + 19922944);
    u16* Xm1_lo   = (u16*)(ws + 20709376);
    u16* Xq_hi    = (u16*)(ws + 21495808);     // 4 MB
    u16* Xq_lo    = (u16*)(ws + 25690112);     // 4 MB
    u16* fhi      = Xq_hi;                     // fused plane aliases Xq planes

    prep_k<<<dim3(992), 256, 0, stream>>>(
        query, mem0, mem1, Wq, Wk0, Wv0, Wk1, Wv1, Wfuse,
        Xq_hi, Xq_lo, Xm0_hi, Xm0_lo, Xm1_hi, Xm1_lo, Whi, Wlo);

    projmm_k<<<dim3(208), 256, 0, stream>>>(
        Xq_hi, Xq_lo, Xm0_hi, Xm0_lo, Xm1_hi, Xm1_lo, Whi, Wlo,
        bq, bk0, bv0, bk1, bv1, qT, k0T, v0T, k1T, v1T);

    attn_k<<<dim3(2048), 256, 0, stream>>>(qT, k0T, v0T, k1T, v1T, fhi);

    fusemm_k<<<dim3(128), 256, 0, stream>>>(Whi, Wlo, fhi, bfuse, out);
}